// Round 1
// baseline (446.794 us; speedup 1.0000x reference)
//
#include <hip/hip_runtime.h>
#include <math.h>

#define C_ 256
#define H_ 512
#define W_ 512
#define HW_ (H_*W_)      // 262144
#define HD_ 128
#define WD_ 128
#define P_ (HD_*WD_)     // 16384
#define NN_ 32
#define GR_ 86
#define NSL_ 128

// ws layout (float offsets)
#define XD_OFF    0ull
#define SDS_OFF   4194304ull
#define GT_OFF    8388608ull
#define GPART_OFF 8650752ull
#define G_OFF     9641984ull
#define S_OFF     9649408ull
#define NSQ_OFF   9649664ull
#define GSUM_OFF  9649696ull
#define BETA_OFF  9649728ull
#define M_OFF     9649984ull
#define DST_OFF   9672512ull
#define SCALE_OFF 9677120ull

__device__ __forceinline__ float wsum64(float v) {
#pragma unroll
    for (int off = 32; off > 0; off >>= 1) v += __shfl_down(v, off, 64);
    return v;
}

__global__ void k_zero(float* p) {
    p[threadIdx.x] = 0.f;   // zeros nsq[32] + pad + gsum
}

// 4x4 maxpool: x (C,H,W) -> xd (C, 128*128)
__global__ void k_pool(const float* __restrict__ x, float* __restrict__ xd) {
    int idx = blockIdx.x * 256 + threadIdx.x;
    int c = idx >> 14;
    int hw = idx & 16383;
    int h = hw >> 7, w = hw & 127;
    const float* xr = x + (size_t)c * HW_ + (size_t)(4 * h) * W_ + 4 * w;
    float4 r0 = *(const float4*)xr;
    float4 r1 = *(const float4*)(xr + W_);
    float4 r2 = *(const float4*)(xr + 2 * W_);
    float4 r3 = *(const float4*)(xr + 3 * W_);
    float m0 = fmaxf(fmaxf(r0.x, r0.y), fmaxf(r0.z, r0.w));
    float m1 = fmaxf(fmaxf(r1.x, r1.y), fmaxf(r1.z, r1.w));
    float m2 = fmaxf(fmaxf(r2.x, r2.y), fmaxf(r2.z, r2.w));
    float m3 = fmaxf(fmaxf(r3.x, r3.y), fmaxf(r3.z, r3.w));
    xd[idx] = fmaxf(fmaxf(m0, m1), fmaxf(m2, m3));
}

// copy noise channels to output nf + accumulate per-channel sumsq
__global__ void k_nf(const float* __restrict__ x, const int* __restrict__ nidx,
                     float* __restrict__ outnf, float* __restrict__ nsq) {
    int n = blockIdx.y;
    int nc = nidx[n];
    int i4 = blockIdx.x * 256 + threadIdx.x;
    float4 v = ((const float4*)(x + (size_t)nc * HW_))[i4];
    ((float4*)(outnf + (size_t)n * HW_))[i4] = v;
    float ss = v.x * v.x + v.y * v.y + v.z * v.z + v.w * v.w;
    __shared__ float red[4];
    float t = wsum64(ss);
    int wid = threadIdx.x >> 6, ln = threadIdx.x & 63;
    if (ln == 0) red[wid] = t;
    __syncthreads();
    if (threadIdx.x == 0) atomicAdd(&nsq[n], red[0] + red[1] + red[2] + red[3]);
}

// g_t[ab][hw] = (1/32) sum_n x[nc][(4h+a)*W + 4w+b] / max(||x_nc||,1e-12); also gsum
__global__ void k_g(const float* __restrict__ x, const int* __restrict__ nidx,
                    const float* __restrict__ nsq, float* __restrict__ gt,
                    float* __restrict__ gsum) {
    __shared__ float inv_[NN_];
    __shared__ int ncs[NN_];
    int tid = threadIdx.x;
    if (tid < NN_) {
        inv_[tid] = 1.f / fmaxf(sqrtf(nsq[tid]), 1e-12f);
        ncs[tid] = nidx[tid];
    }
    __syncthreads();
    int ab = blockIdx.y;
    int a = ab >> 2, b = ab & 3;
    int hw = blockIdx.x * 256 + tid;
    int h = hw >> 7, w = hw & 127;
    size_t off = (size_t)(4 * h + a) * W_ + 4 * w + b;
    float acc = 0.f;
#pragma unroll
    for (int n = 0; n < NN_; n++) acc += x[(size_t)ncs[n] * HW_ + off] * inv_[n];
    float g = acc * (1.f / 32.f);
    gt[(size_t)ab * P_ + hw] = g;
    __shared__ float red[4];
    float t = wsum64(g);
    int wid = tid >> 6, ln = tid & 63;
    if (ln == 0) red[wid] = t;
    __syncthreads();
    if (tid == 0) atomicAdd(gsum, red[0] + red[1] + red[2] + red[3]);
}

// S[r] = sum_p xd[r][p]
__global__ void k_rowsum(const float* __restrict__ xd, float* __restrict__ S) {
    int r = blockIdx.x, tid = threadIdx.x;
    const float4* xp = (const float4*)(xd + (size_t)r * P_);
    float s = 0.f;
#pragma unroll
    for (int k = 0; k < 16; k++) {
        float4 v = xp[k * 256 + tid];
        s += v.x + v.y + v.z + v.w;
    }
    __shared__ float red[4];
    float t = wsum64(s);
    int wid = tid >> 6, ln = tid & 63;
    if (ln == 0) red[wid] = t;
    __syncthreads();
    if (tid == 0) S[r] = red[0] + red[1] + red[2] + red[3];
}

// partial Gram per p-slice: gpart[slice][ga*88+gb] = sum_{p in slice} xd[ga][p]*xd[85+gb][p]
__global__ void k_gram(const float* __restrict__ xd, float* __restrict__ gpart) {
    __shared__ float As[32][132];
    __shared__ float Bs[32][132];
    int tid = threadIdx.x;
    int tx = tid & 15, ty = tid >> 4;
    int p0 = blockIdx.x * 128;
    float acc[8][8];
#pragma unroll
    for (int i = 0; i < 8; i++)
#pragma unroll
        for (int j = 0; j < 8; j++) acc[i][j] = 0.f;
    for (int ch = 0; ch < 4; ch++) {
        int pb = p0 + ch * 32;
        __syncthreads();
#pragma unroll
        for (int kk = 0; kk < 16; kk++) {
            int lin = kk * 256 + tid;
            int row = lin >> 5;
            int pp = lin & 31;
            float av = 0.f, bv = 0.f;
            if (row < GR_) {
                av = xd[(size_t)row * P_ + pb + pp];
                bv = xd[(size_t)(85 + row) * P_ + pb + pp];
            }
            As[pp][row] = av;
            Bs[pp][row] = bv;
        }
        __syncthreads();
        for (int pp = 0; pp < 32; pp++) {
            float4 fa0 = *(const float4*)&As[pp][8 * tx];
            float4 fa1 = *(const float4*)&As[pp][8 * tx + 4];
            float4 fb0 = *(const float4*)&Bs[pp][8 * ty];
            float4 fb1 = *(const float4*)&Bs[pp][8 * ty + 4];
            float fa[8] = {fa0.x, fa0.y, fa0.z, fa0.w, fa1.x, fa1.y, fa1.z, fa1.w};
            float fb[8] = {fb0.x, fb0.y, fb0.z, fb0.w, fb1.x, fb1.y, fb1.z, fb1.w};
#pragma unroll
            for (int ii = 0; ii < 8; ii++)
#pragma unroll
                for (int jj = 0; jj < 8; jj++) acc[ii][jj] += fa[ii] * fb[jj];
        }
    }
    float* gp = gpart + (size_t)blockIdx.x * 7744;
#pragma unroll
    for (int ii = 0; ii < 8; ii++) {
        int ga = 8 * tx + ii;
        if (ga < GR_) {
#pragma unroll
            for (int jj = 0; jj < 8; jj++) {
                int gb = 8 * ty + jj;
                if (gb < GR_) gp[ga * 88 + gb] = acc[ii][jj];
            }
        }
    }
}

__global__ void k_gred(const float* __restrict__ gpart, float* __restrict__ G) {
    int idx = blockIdx.x * 256 + threadIdx.x;
    if (idx >= GR_ * GR_) return;
    int a = idx / GR_, b = idx - a * GR_;
    float s = 0.f;
    for (int sl = 0; sl < NSL_; sl++) s += gpart[(size_t)sl * 7744 + a * 88 + b];
    G[idx] = s;
}

// per-row softmax -> M[i][r] (r indexes v source rows 170..255), beta[i]
__global__ void k_attn(const int* __restrict__ labels, const float* __restrict__ wqkv,
                       const float* __restrict__ bqkv, const float* __restrict__ G,
                       const float* __restrict__ S, float* __restrict__ M,
                       float* __restrict__ beta) {
    int i = blockIdx.x, j = threadIdx.x;
    __shared__ float Mloc[GR_];
    __shared__ float red[4];
    __shared__ float bc;
    int li = labels[i];
    if (li < 0) {
        if (j < GR_) M[i * 88 + j] = 0.f;
        if (j == 0) beta[i] = 0.f;
        return;
    }
    if (j < GR_) Mloc[j] = 0.f;
    int a = i / 3;
    float wq = wqkv[i], bq = bqkv[i];
    int kidx = 256 + j;
    int bk = kidx / 3;
    float wk = wqkv[kidx], bkb = bqkv[kidx];
    int lj = labels[j];
    bool same = (lj == li);
    float score = -3.0e38f;
    if (same)
        score = wq * wk * G[a * GR_ + (bk - 85)] + wq * bkb * S[a] + bq * wk * S[bk] +
                16384.f * bq * bkb;
    int wid = j >> 6, ln = j & 63;
    // max
    float m = score;
#pragma unroll
    for (int off = 32; off > 0; off >>= 1) m = fmaxf(m, __shfl_down(m, off, 64));
    if (ln == 0) red[wid] = m;
    __syncthreads();
    if (j == 0) bc = fmaxf(fmaxf(red[0], red[1]), fmaxf(red[2], red[3]));
    __syncthreads();
    float mx = bc;
    float e = same ? expf(score - mx) : 0.f;
    __syncthreads();
    // sum
    float t = wsum64(e);
    if (ln == 0) red[wid] = t;
    __syncthreads();
    if (j == 0) bc = red[0] + red[1] + red[2] + red[3];
    __syncthreads();
    float attn = e / bc;
    int vidx = 512 + j;
    int vr = vidx / 3 - 170;
    float wv = wqkv[vidx], bv = bqkv[vidx];
    __syncthreads();
    float bp = wsum64(attn * bv);
    if (ln == 0) red[wid] = bp;
    __syncthreads();
    if (j == 0) beta[i] = red[0] + red[1] + red[2] + red[3];
    atomicAdd(&Mloc[vr], attn * wv);
    __syncthreads();
    if (j < GR_) M[i * 88 + j] = Mloc[j];
}

// out_ds[i][p] = beta[i] + sum_r M[i][r] * xd[170+r][p]
__global__ void k_outds(const float* __restrict__ xd, const float* __restrict__ M,
                        const float* __restrict__ beta, float* __restrict__ sds) {
    __shared__ float xv[GR_][128];
    int tid = threadIdx.x;  // 128 threads
    int p = blockIdx.x * 128 + tid;
    int i0 = blockIdx.y * 32;
    for (int r = 0; r < GR_; r++) xv[r][tid] = xd[(size_t)(170 + r) * P_ + p];
    __syncthreads();
    float acc[32];
#pragma unroll
    for (int ii = 0; ii < 32; ii++) acc[ii] = beta[i0 + ii];
    for (int r = 0; r < GR_; r++) {
        float xvv = xv[r][tid];
#pragma unroll
        for (int ii = 0; ii < 32; ii++) acc[ii] += M[(i0 + ii) * 88 + r] * xvv;
    }
#pragma unroll
    for (int ii = 0; ii < 32; ii++) sds[(size_t)(i0 + ii) * P_ + p] = acc[ii];
}

// per-channel stats: D[16], sum, sumsq
__global__ void k_stats(const float* __restrict__ sds, const float* __restrict__ gt,
                        float* __restrict__ dst) {
    int c = blockIdx.x;
    int tid = threadIdx.x;
    const float4* sp = (const float4*)(sds + (size_t)c * P_);
    float d[16];
#pragma unroll
    for (int ab = 0; ab < 16; ab++) d[ab] = 0.f;
    float s1 = 0.f, s2 = 0.f;
    for (int k = 0; k < 16; k++) {
        int p4 = k * 256 + tid;
        float4 v = sp[p4];
        s1 += v.x + v.y + v.z + v.w;
        s2 += v.x * v.x + v.y * v.y + v.z * v.z + v.w * v.w;
#pragma unroll
        for (int ab = 0; ab < 16; ab++) {
            float4 g = ((const float4*)(gt + (size_t)ab * P_))[p4];
            d[ab] += v.x * g.x + v.y * g.y + v.z * g.z + v.w * g.w;
        }
    }
    __shared__ float red[4][18];
    float vals[18];
#pragma unroll
    for (int q = 0; q < 16; q++) vals[q] = d[q];
    vals[16] = s1;
    vals[17] = s2;
#pragma unroll
    for (int q = 0; q < 18; q++) vals[q] = wsum64(vals[q]);
    int wid = tid >> 6, ln = tid & 63;
    if (ln == 0) {
#pragma unroll
        for (int q = 0; q < 18; q++) red[wid][q] = vals[q];
    }
    __syncthreads();
    if (tid < 18) dst[c * 18 + tid] = red[0][tid] + red[1][tid] + red[2][tid] + red[3][tid];
}

__global__ void k_sim(const float* __restrict__ dst, const float* __restrict__ wup,
                      const float* __restrict__ bup, const float* __restrict__ gsum,
                      float* __restrict__ scale) {
    int c = threadIdx.x;
    float gs = gsum[0];
    float wsum = 0.f, wsq = 0.f, dd = 0.f;
#pragma unroll
    for (int ab = 0; ab < 16; ab++) {
        float w = wup[c * 16 + ab];
        wsum += w;
        wsq += w * w;
        dd += w * dst[c * 18 + ab];
    }
    float s1 = dst[c * 18 + 16], s2 = dst[c * 18 + 17];
    float b = bup[c];
    float dot = dd + b * gs;
    float n2 = wsq * s2 + 2.f * b * wsum * s1 + (float)HW_ * b * b;
    float nrm = sqrtf(fmaxf(n2, 0.f));
    float sim = dot / fmaxf(nrm, 1e-12f);
    scale[c] = 1.f - sim;
}

// out = s*w_up + b_up + scale * x
__global__ void k_final(const float* __restrict__ x, const float* __restrict__ sds,
                        const float* __restrict__ wup, const float* __restrict__ bup,
                        const float* __restrict__ scale, float* __restrict__ out) {
    size_t idx = (size_t)blockIdx.x * 256 + threadIdx.x;  // float4 index
    int wq = (int)(idx & 127);
    int y = (int)((idx >> 7) & 511);
    int c = (int)(idx >> 16);
    float sv = sds[(size_t)c * P_ + (size_t)(y >> 2) * WD_ + wq];
    float4 wu = *(const float4*)(wup + c * 16 + (y & 3) * 4);
    float b = bup[c];
    float sc = scale[c];
    float4 xv = ((const float4*)x)[idx];
    float4 o;
    o.x = sv * wu.x + b + sc * xv.x;
    o.y = sv * wu.y + b + sc * xv.y;
    o.z = sv * wu.z + b + sc * xv.z;
    o.w = sv * wu.w + b + sc * xv.w;
    ((float4*)out)[idx] = o;
}

extern "C" void kernel_launch(void* const* d_in, const int* in_sizes, int n_in,
                              void* d_out, int out_size, void* d_ws, size_t ws_size,
                              hipStream_t stream) {
    const float* x = (const float*)d_in[0];
    const int* labels = (const int*)d_in[1];
    const int* nidx = (const int*)d_in[2];
    const float* wqkv = (const float*)d_in[3];
    const float* bqkv = (const float*)d_in[4];
    const float* wup = (const float*)d_in[5];
    const float* bup = (const float*)d_in[6];
    float* out = (float*)d_out;
    float* ws = (float*)d_ws;

    float* xd = ws + XD_OFF;
    float* sds = ws + SDS_OFF;
    float* gt = ws + GT_OFF;
    float* gpart = ws + GPART_OFF;
    float* G = ws + G_OFF;
    float* S = ws + S_OFF;
    float* nsq = ws + NSQ_OFF;
    float* gsum = ws + GSUM_OFF;
    float* beta = ws + BETA_OFF;
    float* M = ws + M_OFF;
    float* dst = ws + DST_OFF;
    float* scale = ws + SCALE_OFF;
    float* outnf = out + (size_t)C_ * HW_;

    k_zero<<<1, 64, 0, stream>>>(ws + NSQ_OFF);
    k_pool<<<16384, 256, 0, stream>>>(x, xd);
    k_nf<<<dim3(256, 32), 256, 0, stream>>>(x, nidx, outnf, nsq);
    k_g<<<dim3(64, 16), 256, 0, stream>>>(x, nidx, nsq, gt, gsum);
    k_rowsum<<<256, 256, 0, stream>>>(xd, S);
    k_gram<<<NSL_, 256, 0, stream>>>(xd, gpart);
    k_gred<<<29, 256, 0, stream>>>(gpart, G);
    k_attn<<<256, 256, 0, stream>>>(labels, wqkv, bqkv, G, S, M, beta);
    k_outds<<<dim3(128, 8), 128, 0, stream>>>(xd, M, beta, sds);
    k_stats<<<256, 256, 0, stream>>>(sds, gt, dst);
    k_sim<<<1, 256, 0, stream>>>(dst, wup, bup, gsum, scale);
    k_final<<<65536, 256, 0, stream>>>(x, sds, wup, bup, scale, out);
}

// Round 2
// 301.584 us; speedup vs baseline: 1.4815x; 1.4815x over previous
//
#include <hip/hip_runtime.h>
#include <math.h>

#define C_ 256
#define H_ 512
#define W_ 512
#define HW_ (H_*W_)      // 262144
#define HD_ 128
#define WD_ 128
#define P_ (HD_*WD_)     // 16384
#define NN_ 32
#define GR_ 86
#define NSL_ 128

// ws layout (float offsets)
#define XD_OFF    0ull
#define SDS_OFF   4194304ull
#define GT_OFF    8388608ull
#define GPART_OFF 8650752ull
#define G_OFF     9641984ull
#define S_OFF     9649408ull
#define NSQ_OFF   9649664ull
#define GSUM_OFF  9649696ull
#define BETA_OFF  9649728ull
#define M_OFF     9649984ull
#define SCALE_OFF 9672512ull

__device__ __forceinline__ float wsum64(float v) {
#pragma unroll
    for (int off = 32; off > 0; off >>= 1) v += __shfl_down(v, off, 64);
    return v;
}

__global__ void k_zero(float* p) {
    int t = threadIdx.x;
    if (t < 289) p[t] = 0.f;   // S[256] + nsq[32] + gsum[1], contiguous
}

// Fused: 4x4 maxpool -> xd ; rowsum -> S ; noise-channel copy -> outnf ; noise sumsq -> nsq
// grid: C_*32 blocks, 256 threads. block b: c=b>>5, seg=b&31 covers xd rows 4*seg..4*seg+3
__global__ void k_pre(const float* __restrict__ x, const int* __restrict__ nidx,
                      float* __restrict__ xd, float* __restrict__ outnf,
                      float* __restrict__ S, float* __restrict__ nsq) {
    int b = blockIdx.x;
    int c = b >> 5, seg = b & 31;
    int t = threadIdx.x;
    __shared__ int sn;
    if (t == 0) {
        int nn = -1;
        for (int n = 0; n < NN_; n++)
            if (nidx[n] == c) nn = n;
        sn = nn;
    }
    __syncthreads();
    int n = sn;
    int wd = t & 127;
    int hl = t >> 7;
    float ssum = 0.f, ss = 0.f;
    const float* xc = x + (size_t)c * HW_;
    float* nfc = outnf + (size_t)(n < 0 ? 0 : n) * HW_;
#pragma unroll
    for (int q = 0; q < 2; q++) {
        int hd = 4 * seg + hl + 2 * q;
        const float4* xr = (const float4*)(xc + (size_t)(4 * hd) * W_) + wd;
        float4 r0 = xr[0], r1 = xr[128], r2 = xr[256], r3 = xr[384];
        if (n >= 0) {
            float4* nr = (float4*)(nfc + (size_t)(4 * hd) * W_) + wd;
            nr[0] = r0; nr[128] = r1; nr[256] = r2; nr[384] = r3;
            ss += r0.x*r0.x + r0.y*r0.y + r0.z*r0.z + r0.w*r0.w
                + r1.x*r1.x + r1.y*r1.y + r1.z*r1.z + r1.w*r1.w
                + r2.x*r2.x + r2.y*r2.y + r2.z*r2.z + r2.w*r2.w
                + r3.x*r3.x + r3.y*r3.y + r3.z*r3.z + r3.w*r3.w;
        }
        float m0 = fmaxf(fmaxf(r0.x, r0.y), fmaxf(r0.z, r0.w));
        float m1 = fmaxf(fmaxf(r1.x, r1.y), fmaxf(r1.z, r1.w));
        float m2 = fmaxf(fmaxf(r2.x, r2.y), fmaxf(r2.z, r2.w));
        float m3 = fmaxf(fmaxf(r3.x, r3.y), fmaxf(r3.z, r3.w));
        float m = fmaxf(fmaxf(m0, m1), fmaxf(m2, m3));
        xd[(size_t)c * P_ + (size_t)hd * WD_ + wd] = m;
        ssum += m;
    }
    __shared__ float red[4];
    float tt = wsum64(ssum);
    int wid = t >> 6, ln = t & 63;
    if (ln == 0) red[wid] = tt;
    __syncthreads();
    if (t == 0) atomicAdd(&S[c], red[0] + red[1] + red[2] + red[3]);
    if (n >= 0) {   // block-uniform branch
        __syncthreads();
        float t2 = wsum64(ss);
        if (ln == 0) red[wid] = t2;
        __syncthreads();
        if (t == 0) atomicAdd(&nsq[n], red[0] + red[1] + red[2] + red[3]);
    }
}

// Coalesced g: grid 128 (pooled row h), 256 threads. thread t: w=t&127, a0=t>>7 (owns a0, a0+2)
// gt[ab][hw] = (1/32) sum_n x[nc][(4h+a)*W + 4w+b] / ||x_nc|| ; also gsum = sum of all g
__global__ void k_g(const float* __restrict__ x, const int* __restrict__ nidx,
                    const float* __restrict__ nsq, float* __restrict__ gt,
                    float* __restrict__ gsum) {
    __shared__ float inv_[NN_];
    __shared__ int ncs[NN_];
    int t = threadIdx.x;
    if (t < NN_) {
        inv_[t] = (1.f / 32.f) / fmaxf(sqrtf(nsq[t]), 1e-12f);
        ncs[t] = nidx[t];
    }
    __syncthreads();
    int h = blockIdx.x;
    int w = t & 127, a0 = t >> 7;
    float acc[2][4] = {{0.f,0.f,0.f,0.f},{0.f,0.f,0.f,0.f}};
#pragma unroll 4
    for (int n = 0; n < NN_; n++) {
        const float* base = x + (size_t)ncs[n] * HW_ + (size_t)(4 * h) * W_ + 4 * w;
        float4 va = *(const float4*)(base + (size_t)a0 * W_);
        float4 vb = *(const float4*)(base + (size_t)(a0 + 2) * W_);
        float iv = inv_[n];
        acc[0][0] += va.x * iv; acc[0][1] += va.y * iv;
        acc[0][2] += va.z * iv; acc[0][3] += va.w * iv;
        acc[1][0] += vb.x * iv; acc[1][1] += vb.y * iv;
        acc[1][2] += vb.z * iv; acc[1][3] += vb.w * iv;
    }
    float gs = 0.f;
#pragma unroll
    for (int q = 0; q < 2; q++) {
        int a = a0 + 2 * q;
#pragma unroll
        for (int bb = 0; bb < 4; bb++) {
            float g = acc[q][bb];
            gt[(size_t)(a * 4 + bb) * P_ + h * WD_ + w] = g;
            gs += g;
        }
    }
    __shared__ float red[4];
    float tt = wsum64(gs);
    int wid = t >> 6, ln = t & 63;
    if (ln == 0) red[wid] = tt;
    __syncthreads();
    if (t == 0) atomicAdd(gsum, red[0] + red[1] + red[2] + red[3]);
}

// partial Gram per p-slice: gpart[slice][ga*88+gb] = sum_{p in slice} xd[ga][p]*xd[85+gb][p]
__global__ void k_gram(const float* __restrict__ xd, float* __restrict__ gpart) {
    __shared__ float As[32][132];
    __shared__ float Bs[32][132];
    int tid = threadIdx.x;
    int tx = tid & 15, ty = tid >> 4;
    int p0 = blockIdx.x * 128;
    float acc[8][8];
#pragma unroll
    for (int i = 0; i < 8; i++)
#pragma unroll
        for (int j = 0; j < 8; j++) acc[i][j] = 0.f;
    for (int ch = 0; ch < 4; ch++) {
        int pb = p0 + ch * 32;
        __syncthreads();
#pragma unroll
        for (int kk = 0; kk < 16; kk++) {
            int lin = kk * 256 + tid;
            int row = lin >> 5;
            int pp = lin & 31;
            float av = 0.f, bv = 0.f;
            if (row < GR_) {
                av = xd[(size_t)row * P_ + pb + pp];
                bv = xd[(size_t)(85 + row) * P_ + pb + pp];
            }
            As[pp][row] = av;
            Bs[pp][row] = bv;
        }
        __syncthreads();
        for (int pp = 0; pp < 32; pp++) {
            float4 fa0 = *(const float4*)&As[pp][8 * tx];
            float4 fa1 = *(const float4*)&As[pp][8 * tx + 4];
            float4 fb0 = *(const float4*)&Bs[pp][8 * ty];
            float4 fb1 = *(const float4*)&Bs[pp][8 * ty + 4];
            float fa[8] = {fa0.x, fa0.y, fa0.z, fa0.w, fa1.x, fa1.y, fa1.z, fa1.w};
            float fb[8] = {fb0.x, fb0.y, fb0.z, fb0.w, fb1.x, fb1.y, fb1.z, fb1.w};
#pragma unroll
            for (int ii = 0; ii < 8; ii++)
#pragma unroll
                for (int jj = 0; jj < 8; jj++) acc[ii][jj] += fa[ii] * fb[jj];
        }
    }
    float* gp = gpart + (size_t)blockIdx.x * 7744;
#pragma unroll
    for (int ii = 0; ii < 8; ii++) {
        int ga = 8 * tx + ii;
        if (ga < GR_) {
#pragma unroll
            for (int jj = 0; jj < 8; jj++) {
                int gb = 8 * ty + jj;
                if (gb < GR_) gp[ga * 88 + gb] = acc[ii][jj];
            }
        }
    }
}

__global__ void k_gred(const float* __restrict__ gpart, float* __restrict__ G) {
    int idx = blockIdx.x * 256 + threadIdx.x;
    if (idx >= GR_ * GR_) return;
    int a = idx / GR_, b = idx - a * GR_;
    float s = 0.f;
    for (int sl = 0; sl < NSL_; sl++) s += gpart[(size_t)sl * 7744 + a * 88 + b];
    G[idx] = s;
}

// per-row softmax -> M[i][r] (r indexes v source rows 170..255), beta[i]
__global__ void k_attn(const int* __restrict__ labels, const float* __restrict__ wqkv,
                       const float* __restrict__ bqkv, const float* __restrict__ G,
                       const float* __restrict__ S, float* __restrict__ M,
                       float* __restrict__ beta) {
    int i = blockIdx.x, j = threadIdx.x;
    __shared__ float Mloc[GR_];
    __shared__ float red[4];
    __shared__ float bc;
    int li = labels[i];
    if (li < 0) {
        if (j < GR_) M[i * 88 + j] = 0.f;
        if (j == 0) beta[i] = 0.f;
        return;
    }
    if (j < GR_) Mloc[j] = 0.f;
    int a = i / 3;
    float wq = wqkv[i], bq = bqkv[i];
    int kidx = 256 + j;
    int bk = kidx / 3;
    float wk = wqkv[kidx], bkb = bqkv[kidx];
    int lj = labels[j];
    bool same = (lj == li);
    float score = -3.0e38f;
    if (same)
        score = wq * wk * G[a * GR_ + (bk - 85)] + wq * bkb * S[a] + bq * wk * S[bk] +
                16384.f * bq * bkb;
    int wid = j >> 6, ln = j & 63;
    float m = score;
#pragma unroll
    for (int off = 32; off > 0; off >>= 1) m = fmaxf(m, __shfl_down(m, off, 64));
    if (ln == 0) red[wid] = m;
    __syncthreads();
    if (j == 0) bc = fmaxf(fmaxf(red[0], red[1]), fmaxf(red[2], red[3]));
    __syncthreads();
    float mx = bc;
    float e = same ? expf(score - mx) : 0.f;
    __syncthreads();
    float t = wsum64(e);
    if (ln == 0) red[wid] = t;
    __syncthreads();
    if (j == 0) bc = red[0] + red[1] + red[2] + red[3];
    __syncthreads();
    float attn = e / bc;
    int vidx = 512 + j;
    int vr = vidx / 3 - 170;
    float wv = wqkv[vidx], bv = bqkv[vidx];
    __syncthreads();
    float bp = wsum64(attn * bv);
    if (ln == 0) red[wid] = bp;
    __syncthreads();
    if (j == 0) beta[i] = red[0] + red[1] + red[2] + red[3];
    atomicAdd(&Mloc[vr], attn * wv);
    __syncthreads();
    if (j < GR_) M[i * 88 + j] = Mloc[j];
}

// out_ds[i][p] = beta[i] + sum_r M[i][r] * xd[170+r][p]
// grid (64 p-tiles, 16 i-tiles), 256 threads; M tile staged in LDS, read as float4 broadcast
__global__ void k_outds(const float* __restrict__ xd, const float* __restrict__ M,
                        const float* __restrict__ beta, float* __restrict__ sds) {
    __shared__ float Mt[16][88];
    __shared__ float bt[16];
    int t = threadIdx.x;
    int p0 = blockIdx.x * 256;
    int i0 = blockIdx.y * 16;
    for (int idx = t; idx < 16 * 88; idx += 256)
        Mt[idx / 88][idx % 88] = M[(size_t)(i0 + idx / 88) * 88 + (idx % 88)];
    if (t < 16) bt[t] = beta[i0 + t];
    __syncthreads();
    float acc[16];
#pragma unroll
    for (int ii = 0; ii < 16; ii++) acc[ii] = bt[ii];
    const float* xb = xd + (size_t)170 * P_ + p0 + t;
    for (int r = 0; r < 84; r += 4) {
        float x0 = xb[(size_t)r * P_];
        float x1 = xb[(size_t)(r + 1) * P_];
        float x2 = xb[(size_t)(r + 2) * P_];
        float x3 = xb[(size_t)(r + 3) * P_];
#pragma unroll
        for (int ii = 0; ii < 16; ii++) {
            float4 mv = *(const float4*)&Mt[ii][r];
            acc[ii] += mv.x * x0 + mv.y * x1 + mv.z * x2 + mv.w * x3;
        }
    }
    {
        float x0 = xb[(size_t)84 * P_];
        float x1 = xb[(size_t)85 * P_];
#pragma unroll
        for (int ii = 0; ii < 16; ii++)
            acc[ii] += Mt[ii][84] * x0 + Mt[ii][85] * x1;
    }
#pragma unroll
    for (int ii = 0; ii < 16; ii++)
        sds[(size_t)(i0 + ii) * P_ + p0 + t] = acc[ii];
}

// per-channel stats D[16], sum, sumsq  + fused similarity -> scale[c]
__global__ void k_stats(const float* __restrict__ sds, const float* __restrict__ gt,
                        const float* __restrict__ wup, const float* __restrict__ bup,
                        const float* __restrict__ gsum, float* __restrict__ scale) {
    int c = blockIdx.x;
    int tid = threadIdx.x;
    const float4* sp = (const float4*)(sds + (size_t)c * P_);
    float d[16];
#pragma unroll
    for (int ab = 0; ab < 16; ab++) d[ab] = 0.f;
    float s1 = 0.f, s2 = 0.f;
    for (int k = 0; k < 16; k++) {
        int p4 = k * 256 + tid;
        float4 v = sp[p4];
        s1 += v.x + v.y + v.z + v.w;
        s2 += v.x * v.x + v.y * v.y + v.z * v.z + v.w * v.w;
#pragma unroll
        for (int ab = 0; ab < 16; ab++) {
            float4 g = ((const float4*)(gt + (size_t)ab * P_))[p4];
            d[ab] += v.x * g.x + v.y * g.y + v.z * g.z + v.w * g.w;
        }
    }
    __shared__ float red[4][18];
    __shared__ float sv[18];
    float vals[18];
#pragma unroll
    for (int q = 0; q < 16; q++) vals[q] = d[q];
    vals[16] = s1;
    vals[17] = s2;
#pragma unroll
    for (int q = 0; q < 18; q++) vals[q] = wsum64(vals[q]);
    int wid = tid >> 6, ln = tid & 63;
    if (ln == 0) {
#pragma unroll
        for (int q = 0; q < 18; q++) red[wid][q] = vals[q];
    }
    __syncthreads();
    if (tid < 18) sv[tid] = red[0][tid] + red[1][tid] + red[2][tid] + red[3][tid];
    __syncthreads();
    if (tid == 0) {
        float gs = gsum[0];
        float wsm = 0.f, wsq = 0.f, dd = 0.f;
#pragma unroll
        for (int ab = 0; ab < 16; ab++) {
            float w = wup[c * 16 + ab];
            wsm += w;
            wsq += w * w;
            dd += w * sv[ab];
        }
        float s1b = sv[16], s2b = sv[17];
        float b = bup[c];
        float dot = dd + b * gs;
        float n2 = wsq * s2b + 2.f * b * wsm * s1b + (float)HW_ * b * b;
        float nrm = sqrtf(fmaxf(n2, 0.f));
        scale[c] = 1.f - dot / fmaxf(nrm, 1e-12f);
    }
}

// out = s*w_up + b_up + scale * x
__global__ void k_final(const float* __restrict__ x, const float* __restrict__ sds,
                        const float* __restrict__ wup, const float* __restrict__ bup,
                        const float* __restrict__ scale, float* __restrict__ out) {
    size_t idx = (size_t)blockIdx.x * 256 + threadIdx.x;  // float4 index
    int wq = (int)(idx & 127);
    int y = (int)((idx >> 7) & 511);
    int c = (int)(idx >> 16);
    float sv = sds[(size_t)c * P_ + (size_t)(y >> 2) * WD_ + wq];
    float4 wu = *(const float4*)(wup + c * 16 + (y & 3) * 4);
    float b = bup[c];
    float sc = scale[c];
    float4 xv = ((const float4*)x)[idx];
    float4 o;
    o.x = sv * wu.x + b + sc * xv.x;
    o.y = sv * wu.y + b + sc * xv.y;
    o.z = sv * wu.z + b + sc * xv.z;
    o.w = sv * wu.w + b + sc * xv.w;
    ((float4*)out)[idx] = o;
}

extern "C" void kernel_launch(void* const* d_in, const int* in_sizes, int n_in,
                              void* d_out, int out_size, void* d_ws, size_t ws_size,
                              hipStream_t stream) {
    const float* x = (const float*)d_in[0];
    const int* labels = (const int*)d_in[1];
    const int* nidx = (const int*)d_in[2];
    const float* wqkv = (const float*)d_in[3];
    const float* bqkv = (const float*)d_in[4];
    const float* wup = (const float*)d_in[5];
    const float* bup = (const float*)d_in[6];
    float* out = (float*)d_out;
    float* ws = (float*)d_ws;

    float* xd = ws + XD_OFF;
    float* sds = ws + SDS_OFF;
    float* gt = ws + GT_OFF;
    float* gpart = ws + GPART_OFF;
    float* G = ws + G_OFF;
    float* S = ws + S_OFF;
    float* nsq = ws + NSQ_OFF;
    float* gsum = ws + GSUM_OFF;
    float* beta = ws + BETA_OFF;
    float* M = ws + M_OFF;
    float* scale = ws + SCALE_OFF;
    float* outnf = out + (size_t)C_ * HW_;

    k_zero<<<1, 512, 0, stream>>>(ws + S_OFF);
    k_pre<<<C_ * 32, 256, 0, stream>>>(x, nidx, xd, outnf, S, nsq);
    k_g<<<128, 256, 0, stream>>>(x, nidx, nsq, gt, gsum);
    k_gram<<<NSL_, 256, 0, stream>>>(xd, gpart);
    k_gred<<<29, 256, 0, stream>>>(gpart, G);
    k_attn<<<256, 256, 0, stream>>>(labels, wqkv, bqkv, G, S, M, beta);
    k_outds<<<dim3(64, 16), 256, 0, stream>>>(xd, M, beta, sds);
    k_stats<<<256, 256, 0, stream>>>(sds, gt, wup, bup, gsum, scale);
    k_final<<<65536, 256, 0, stream>>>(x, sds, wup, bup, scale, out);
}

// Round 4
// 210.080 us; speedup vs baseline: 2.1268x; 1.4356x over previous
//
#include <hip/hip_runtime.h>
#include <math.h>

#define C_ 256
#define H_ 512
#define W_ 512
#define HW_ (H_*W_)      // 262144
#define HD_ 128
#define WD_ 128
#define P_ (HD_*WD_)     // 16384
#define NN_ 32
#define GR_ 86
#define NSL_ 128

// ws layout (float offsets)
#define XD_OFF     0ull
#define SDS_OFF    4194304ull
#define GT_OFF     8388608ull
#define GPART_OFF  8650752ull   // 128*7744 = 991232 floats; dead after k_attn
#define DSTP_OFF   8650752ull   // aliases gpart: 256*64*18 = 294912 (written by k_outds)
#define S_OFF      9641984ull   // 256
#define SPART_OFF  9642240ull   // 8192
#define NSQP_OFF   9650432ull   // 1024
#define GSUMP_OFF  9651456ull   // 128
#define BETA_OFF   9651584ull   // 256
#define M_OFF      9651840ull   // 256*88 = 22528
#define SCALE_OFF  9674368ull   // 256  -> end 9674624 floats = 38.7 MB

typedef float nfloat4 __attribute__((ext_vector_type(4)));

__device__ __forceinline__ void nt_store4(float4 v, float* p) {
    nfloat4 nv;
    nv.x = v.x; nv.y = v.y; nv.z = v.z; nv.w = v.w;
    __builtin_nontemporal_store(nv, (nfloat4*)p);
}

__device__ __forceinline__ float wsum64(float v) {
#pragma unroll
    for (int off = 32; off > 0; off >>= 1) v += __shfl_down(v, off, 64);
    return v;
}

// Fused: 4x4 maxpool -> xd ; rowsum partials -> Spart ; noise copy -> outnf ; noise sumsq -> nsqp
// grid: C_*32 blocks, 256 threads. block b: c=b>>5, seg=b&31 covers xd rows 4*seg..4*seg+3
__global__ void __launch_bounds__(256) k_pre(
        const float* __restrict__ x, const int* __restrict__ nidx,
        float* __restrict__ xd, float* __restrict__ outnf,
        float* __restrict__ Spart, float* __restrict__ nsqp) {
    int b = blockIdx.x;
    int c = b >> 5, seg = b & 31;
    int t = threadIdx.x;
    __shared__ int sn;
    if (t == 0) {
        int nn = -1;
        for (int n = 0; n < NN_; n++)
            if (nidx[n] == c) nn = n;
        sn = nn;
    }
    __syncthreads();
    int n = sn;
    int wd = t & 127;
    int hl = t >> 7;
    float ssum = 0.f, ss = 0.f;
    const float* xc = x + (size_t)c * HW_;
    float* nfc = outnf + (size_t)(n < 0 ? 0 : n) * HW_;
#pragma unroll
    for (int q = 0; q < 2; q++) {
        int hd = 4 * seg + hl + 2 * q;
        const float4* xr = (const float4*)(xc + (size_t)(4 * hd) * W_) + wd;
        float4 r0 = xr[0], r1 = xr[128], r2 = xr[256], r3 = xr[384];
        if (n >= 0) {
            float* nr = nfc + (size_t)(4 * hd) * W_ + 4 * wd;
            nt_store4(r0, nr);
            nt_store4(r1, nr + 512);
            nt_store4(r2, nr + 1024);
            nt_store4(r3, nr + 1536);
            ss += r0.x*r0.x + r0.y*r0.y + r0.z*r0.z + r0.w*r0.w
                + r1.x*r1.x + r1.y*r1.y + r1.z*r1.z + r1.w*r1.w
                + r2.x*r2.x + r2.y*r2.y + r2.z*r2.z + r2.w*r2.w
                + r3.x*r3.x + r3.y*r3.y + r3.z*r3.z + r3.w*r3.w;
        }
        float m0 = fmaxf(fmaxf(r0.x, r0.y), fmaxf(r0.z, r0.w));
        float m1 = fmaxf(fmaxf(r1.x, r1.y), fmaxf(r1.z, r1.w));
        float m2 = fmaxf(fmaxf(r2.x, r2.y), fmaxf(r2.z, r2.w));
        float m3 = fmaxf(fmaxf(r3.x, r3.y), fmaxf(r3.z, r3.w));
        float m = fmaxf(fmaxf(m0, m1), fmaxf(m2, m3));
        xd[(size_t)c * P_ + (size_t)hd * WD_ + wd] = m;
        ssum += m;
    }
    __shared__ float red[4];
    float tt = wsum64(ssum);
    int wid = t >> 6, ln = t & 63;
    if (ln == 0) red[wid] = tt;
    __syncthreads();
    if (t == 0) Spart[c * 32 + seg] = red[0] + red[1] + red[2] + red[3];
    if (n >= 0) {   // block-uniform branch
        __syncthreads();
        float t2 = wsum64(ss);
        if (ln == 0) red[wid] = t2;
        __syncthreads();
        if (t == 0) nsqp[n * 32 + seg] = red[0] + red[1] + red[2] + red[3];
    }
}

// Merged mid kernel: bid<128 -> g-plane row h=bid ; 128<=bid<256 -> gram slice ; bid==256 -> S reduce
__global__ void __launch_bounds__(256) k_mid(
        const float* __restrict__ x, const int* __restrict__ nidx,
        const float* __restrict__ nsqp, const float* __restrict__ Spart,
        const float* __restrict__ xd,
        float* __restrict__ gt, float* __restrict__ gsump,
        float* __restrict__ gpart, float* __restrict__ S) {
    __shared__ float smem[2 * 32 * 132];   // 33 KB, shared across branch types
    int bid = blockIdx.x;
    int t = threadIdx.x;
    if (bid < 128) {
        // ---- g: gt[ab][hw] = (1/32) sum_n x[nc][(4h+a)*W+4w+b] / ||x_nc|| ----
        float* inv_ = smem;
        int* ncs = (int*)(smem + 32);
        float* red = smem + 64;
        if (t < NN_) {
            const float* np = nsqp + t * 32;
            float s = 0.f;
#pragma unroll
            for (int k = 0; k < 32; k++) s += np[k];
            inv_[t] = (1.f / 32.f) / fmaxf(sqrtf(s), 1e-12f);
            ncs[t] = nidx[t];
        }
        __syncthreads();
        int h = bid;
        int w = t & 127, a0 = t >> 7;
        float acc[2][4] = {{0.f,0.f,0.f,0.f},{0.f,0.f,0.f,0.f}};
#pragma unroll 4
        for (int n = 0; n < NN_; n++) {
            const float* base = x + (size_t)ncs[n] * HW_ + (size_t)(4 * h) * W_ + 4 * w;
            float4 va = *(const float4*)(base + (size_t)a0 * W_);
            float4 vb = *(const float4*)(base + (size_t)(a0 + 2) * W_);
            float iv = inv_[n];
            acc[0][0] += va.x * iv; acc[0][1] += va.y * iv;
            acc[0][2] += va.z * iv; acc[0][3] += va.w * iv;
            acc[1][0] += vb.x * iv; acc[1][1] += vb.y * iv;
            acc[1][2] += vb.z * iv; acc[1][3] += vb.w * iv;
        }
        float gs = 0.f;
#pragma unroll
        for (int q = 0; q < 2; q++) {
            int a = a0 + 2 * q;
#pragma unroll
            for (int bb = 0; bb < 4; bb++) {
                float g = acc[q][bb];
                gt[(size_t)(a * 4 + bb) * P_ + h * WD_ + w] = g;
                gs += g;
            }
        }
        float tt = wsum64(gs);
        int wid = t >> 6, ln = t & 63;
        if (ln == 0) red[wid] = tt;
        __syncthreads();
        if (t == 0) gsump[bid] = red[0] + red[1] + red[2] + red[3];
    } else if (bid < 128 + NSL_) {
        // ---- gram slice: gpart[sl][ga*88+gb] = sum_{p in slice} xd[ga][p]*xd[85+gb][p] ----
        int sl = bid - 128;
        float (*As)[132] = (float(*)[132])smem;
        float (*Bs)[132] = (float(*)[132])(smem + 32 * 132);
        int tx = t & 15, ty = t >> 4;
        int p0 = sl * 128;
        float acc[8][8];
#pragma unroll
        for (int i = 0; i < 8; i++)
#pragma unroll
            for (int j = 0; j < 8; j++) acc[i][j] = 0.f;
        for (int ch = 0; ch < 4; ch++) {
            int pb = p0 + ch * 32;
            __syncthreads();
#pragma unroll
            for (int kk = 0; kk < 16; kk++) {
                int lin = kk * 256 + t;
                int row = lin >> 5;
                int pp = lin & 31;
                float av = 0.f, bv = 0.f;
                if (row < GR_) {
                    av = xd[(size_t)row * P_ + pb + pp];
                    bv = xd[(size_t)(85 + row) * P_ + pb + pp];
                }
                As[pp][row] = av;
                Bs[pp][row] = bv;
            }
            __syncthreads();
            for (int pp = 0; pp < 32; pp++) {
                float4 fa0 = *(const float4*)&As[pp][8 * tx];
                float4 fa1 = *(const float4*)&As[pp][8 * tx + 4];
                float4 fb0 = *(const float4*)&Bs[pp][8 * ty];
                float4 fb1 = *(const float4*)&Bs[pp][8 * ty + 4];
                float fa[8] = {fa0.x, fa0.y, fa0.z, fa0.w, fa1.x, fa1.y, fa1.z, fa1.w};
                float fb[8] = {fb0.x, fb0.y, fb0.z, fb0.w, fb1.x, fb1.y, fb1.z, fb1.w};
#pragma unroll
                for (int ii = 0; ii < 8; ii++)
#pragma unroll
                    for (int jj = 0; jj < 8; jj++) acc[ii][jj] += fa[ii] * fb[jj];
            }
        }
        float* gp = gpart + (size_t)sl * 7744;
#pragma unroll
        for (int ii = 0; ii < 8; ii++) {
            int ga = 8 * tx + ii;
            if (ga < GR_) {
#pragma unroll
                for (int jj = 0; jj < 8; jj++) {
                    int gb = 8 * ty + jj;
                    if (gb < GR_) gp[ga * 88 + gb] = acc[ii][jj];
                }
            }
        }
    } else {
        // ---- S reduce ----
        if (t < C_) {
            const float* sp = Spart + t * 32;
            float s = 0.f;
#pragma unroll
            for (int k = 0; k < 32; k++) s += sp[k];
            S[t] = s;
        }
    }
}

// per-row softmax -> M[i][r], beta[i]; G-row reduced from gpart in prologue
__global__ void __launch_bounds__(256) k_attn(
        const int* __restrict__ labels, const float* __restrict__ wqkv,
        const float* __restrict__ bqkv, const float* __restrict__ gpart,
        const float* __restrict__ S, float* __restrict__ M,
        float* __restrict__ beta) {
    int i = blockIdx.x, j = threadIdx.x;
    __shared__ float grow[GR_];
    __shared__ float Mloc[GR_];
    __shared__ float red[4];
    __shared__ float bc;
    int li = labels[i];
    if (li < 0) {
        if (j < GR_) M[i * 88 + j] = 0.f;
        if (j == 0) beta[i] = 0.f;
        return;
    }
    int a = i / 3;
    if (j < GR_) {
        Mloc[j] = 0.f;
        const float* gp = gpart + (size_t)a * 88 + j;
        float s = 0.f;
#pragma unroll 8
        for (int sl = 0; sl < NSL_; sl++) s += gp[(size_t)sl * 7744];
        grow[j] = s;
    }
    __syncthreads();
    float wq = wqkv[i], bq = bqkv[i];
    int kidx = 256 + j;
    int bk = kidx / 3;
    float wk = wqkv[kidx], bkb = bqkv[kidx];
    int lj = labels[j];
    bool same = (lj == li);
    float score = -3.0e38f;
    if (same)
        score = wq * wk * grow[bk - 85] + wq * bkb * S[a] + bq * wk * S[bk] +
                16384.f * bq * bkb;
    int wid = j >> 6, ln = j & 63;
    float m = score;
#pragma unroll
    for (int off = 32; off > 0; off >>= 1) m = fmaxf(m, __shfl_down(m, off, 64));
    if (ln == 0) red[wid] = m;
    __syncthreads();
    if (j == 0) bc = fmaxf(fmaxf(red[0], red[1]), fmaxf(red[2], red[3]));
    __syncthreads();
    float mx = bc;
    float e = same ? expf(score - mx) : 0.f;
    __syncthreads();
    float t = wsum64(e);
    if (ln == 0) red[wid] = t;
    __syncthreads();
    if (j == 0) bc = red[0] + red[1] + red[2] + red[3];
    __syncthreads();
    float attn = e / bc;
    int vidx = 512 + j;
    int vr = vidx / 3 - 170;
    float wv = wqkv[vidx], bv = bqkv[vidx];
    __syncthreads();
    float bp = wsum64(attn * bv);
    if (ln == 0) red[wid] = bp;
    __syncthreads();
    if (j == 0) beta[i] = red[0] + red[1] + red[2] + red[3];
    atomicAdd(&Mloc[vr], attn * wv);
    __syncthreads();
    if (j < GR_) M[i * 88 + j] = Mloc[j];
}

// out_ds + fused per-channel stats partials.
// grid (64 p-tiles, 16 i-tiles), 256 threads.
__global__ void __launch_bounds__(256) k_outds(
        const float* __restrict__ xd, const float* __restrict__ gt,
        const float* __restrict__ M, const float* __restrict__ beta,
        float* __restrict__ sds, float* __restrict__ dstp) {
    __shared__ float Mt[16][88];
    __shared__ float bt[16];
    __shared__ float sdsL[16][258];
    __shared__ float gtsL[16][258];
    int t = threadIdx.x;
    int p0 = blockIdx.x * 256;
    int i0 = blockIdx.y * 16;
    for (int idx = t; idx < 16 * 88; idx += 256)
        Mt[idx / 88][idx % 88] = M[(size_t)(i0 + idx / 88) * 88 + (idx % 88)];
    if (t < 16) bt[t] = beta[i0 + t];
#pragma unroll 4
    for (int ab = 0; ab < 16; ab++)
        gtsL[ab][t] = gt[(size_t)ab * P_ + p0 + t];
    __syncthreads();
    float acc[16];
#pragma unroll
    for (int ii = 0; ii < 16; ii++) acc[ii] = bt[ii];
    const float* xb = xd + (size_t)170 * P_ + p0 + t;
    for (int r = 0; r < 84; r += 4) {
        float x0 = xb[(size_t)r * P_];
        float x1 = xb[(size_t)(r + 1) * P_];
        float x2 = xb[(size_t)(r + 2) * P_];
        float x3 = xb[(size_t)(r + 3) * P_];
#pragma unroll
        for (int ii = 0; ii < 16; ii++) {
            float4 mv = *(const float4*)&Mt[ii][r];
            acc[ii] += mv.x * x0 + mv.y * x1 + mv.z * x2 + mv.w * x3;
        }
    }
    {
        float x0 = xb[(size_t)84 * P_];
        float x1 = xb[(size_t)85 * P_];
#pragma unroll
        for (int ii = 0; ii < 16; ii++)
            acc[ii] += Mt[ii][84] * x0 + Mt[ii][85] * x1;
    }
#pragma unroll
    for (int ii = 0; ii < 16; ii++) {
        sds[(size_t)(i0 + ii) * P_ + p0 + t] = acc[ii];
        sdsL[ii][t] = acc[ii];
    }
    __syncthreads();
    // phase 2: D[ch][ab] = sum_t sdsL[ch][t]*gtsL[ab][t]; s1/s2 on threads 0..31
    int ch = t & 15, ab = t >> 4;
    bool do1 = (t < 16), do2 = (t >= 16 && t < 32);
    float D = 0.f, sx = 0.f;
    for (int k = 0; k < 256; k++) {
        float sv = sdsL[ch][k];
        float gv = gtsL[ab][k];
        D += sv * gv;
        if (do1) sx += sv;
        if (do2) sx += sv * sv;
    }
    size_t base = ((size_t)(i0 + ch) * 64 + blockIdx.x) * 18;
    dstp[base + ab] = D;
    if (do1) dstp[base + 16] = sx;
    if (do2) dstp[base + 17] = sx;
}

// reduce dstpart + gsump -> scale[c]. grid 256 blocks x 64 threads.
__global__ void __launch_bounds__(64) k_sim(
        const float* __restrict__ dstp, const float* __restrict__ gsump,
        const float* __restrict__ wup, const float* __restrict__ bup,
        float* __restrict__ scale) {
    int c = blockIdx.x, t = threadIdx.x;
    const float* dp = dstp + ((size_t)c * 64 + t) * 18;
    float vals[19];
#pragma unroll
    for (int q = 0; q < 18; q++) vals[q] = dp[q];
    vals[18] = gsump[t] + gsump[t + 64];
#pragma unroll
    for (int q = 0; q < 19; q++) vals[q] = wsum64(vals[q]);
    if (t == 0) {
        float gs = vals[18];
        float wsm = 0.f, wsq = 0.f, dd = 0.f;
#pragma unroll
        for (int ab = 0; ab < 16; ab++) {
            float w = wup[c * 16 + ab];
            wsm += w;
            wsq += w * w;
            dd += w * vals[ab];
        }
        float s1 = vals[16], s2 = vals[17];
        float b = bup[c];
        float dot = dd + b * gs;
        float n2 = wsq * s2 + 2.f * b * wsm * s1 + (float)HW_ * b * b;
        float nrm = sqrtf(fmaxf(n2, 0.f));
        scale[c] = 1.f - dot / fmaxf(nrm, 1e-12f);
    }
}

// out = s*w_up + b_up + scale * x
__global__ void __launch_bounds__(256) k_final(
        const float* __restrict__ x, const float* __restrict__ sds,
        const float* __restrict__ wup, const float* __restrict__ bup,
        const float* __restrict__ scale, float* __restrict__ out) {
    size_t idx = (size_t)blockIdx.x * 256 + threadIdx.x;  // float4 index
    int wq = (int)(idx & 127);
    int y = (int)((idx >> 7) & 511);
    int c = (int)(idx >> 16);
    float sv = sds[(size_t)c * P_ + (size_t)(y >> 2) * WD_ + wq];
    float4 wu = *(const float4*)(wup + c * 16 + (y & 3) * 4);
    float b = bup[c];
    float sc = scale[c];
    float4 xv = ((const float4*)x)[idx];
    float4 o;
    o.x = sv * wu.x + b + sc * xv.x;
    o.y = sv * wu.y + b + sc * xv.y;
    o.z = sv * wu.z + b + sc * xv.z;
    o.w = sv * wu.w + b + sc * xv.w;
    nt_store4(o, out + 4 * idx);
}

extern "C" void kernel_launch(void* const* d_in, const int* in_sizes, int n_in,
                              void* d_out, int out_size, void* d_ws, size_t ws_size,
                              hipStream_t stream) {
    const float* x = (const float*)d_in[0];
    const int* labels = (const int*)d_in[1];
    const int* nidx = (const int*)d_in[2];
    const float* wqkv = (const float*)d_in[3];
    const float* bqkv = (const float*)d_in[4];
    const float* wup = (const float*)d_in[5];
    const float* bup = (const float*)d_in[6];
    float* out = (float*)d_out;
    float* ws = (float*)d_ws;

    float* xd = ws + XD_OFF;
    float* sds = ws + SDS_OFF;
    float* gt = ws + GT_OFF;
    float* gpart = ws + GPART_OFF;
    float* dstp = ws + DSTP_OFF;
    float* S = ws + S_OFF;
    float* Spart = ws + SPART_OFF;
    float* nsqp = ws + NSQP_OFF;
    float* gsump = ws + GSUMP_OFF;
    float* beta = ws + BETA_OFF;
    float* M = ws + M_OFF;
    float* scale = ws + SCALE_OFF;
    float* outnf = out + (size_t)C_ * HW_;

    k_pre<<<C_ * 32, 256, 0, stream>>>(x, nidx, xd, outnf, Spart, nsqp);
    k_mid<<<128 + NSL_ + 1, 256, 0, stream>>>(x, nidx, nsqp, Spart, xd, gt, gsump, gpart, S);
    k_attn<<<256, 256, 0, stream>>>(labels, wqkv, bqkv, gpart, S, M, beta);
    k_outds<<<dim3(64, 16), 256, 0, stream>>>(xd, gt, M, beta, sds, dstp);
    k_sim<<<256, 64, 0, stream>>>(dstp, gsump, wup, bup, scale);
    k_final<<<65536, 256, 0, stream>>>(x, sds, wup, bup, scale, out);
}